// Round 9
// baseline (451.757 us; speedup 1.0000x reference)
//
#include <hip/hip_runtime.h>
#include <hip/hip_bf16.h>

// Problem dims (fixed by reference)
#define BATCH 2
#define SEQ   2048
#define DIM   1024
#define IDIM  4096
#define NH    16
#define HD    64
#define TOK   (BATCH * SEQ)      // 4096 token rows

typedef __hip_bfloat16 bf16;

typedef short bf16x8_t __attribute__((ext_vector_type(8)));
typedef float f32x4_t  __attribute__((ext_vector_type(4)));

__device__ __forceinline__ float ldv(const float* p, size_t i) { return p[i]; }
__device__ __forceinline__ float ldv(const bf16*  p, size_t i) { return __bfloat162float(p[i]); }
__device__ __forceinline__ void  stv(float* p, size_t i, float v) { p[i] = v; }
__device__ __forceinline__ void  stv(bf16*  p, size_t i, float v) { p[i] = __float2bfloat16(v); }

__device__ __forceinline__ f32x4_t mfma16(bf16x8_t a, bf16x8_t b, f32x4_t c) {
    return __builtin_amdgcn_mfma_f32_16x16x32_bf16(a, b, c, 0, 0, 0);
}

// async global->LDS, 16B per lane; LDS dest = wave-uniform base + lane*16
__device__ __forceinline__ void gload16(const bf16* g, bf16* l) {
    __builtin_amdgcn_global_load_lds(
        (const __attribute__((address_space(1))) void*)g,
        (__attribute__((address_space(3))) void*)l, 16, 0, 0);
}

// XCD-aware block mapping (verified: cut dualgemm FETCH 277->98.6 MB).
__device__ __forceinline__ void xcd_map(int &bx, int &by) {
    const int gn  = gridDim.x;
    const int lin = blockIdx.y * gn + blockIdx.x;
    const int cx  = gn >> 3;
    const int xcd = lin & 7;
    const int slot = lin >> 3;
    bx = xcd * cx + slot % cx;
    by = slot / cx;
}

// ---------------------------------------------------------------------------
// LayerNorm row (1 wave per row): float4 loads, shfl_xor reduce, ushort4 out.
// ---------------------------------------------------------------------------
__device__ __forceinline__ void ln_one_row(const float* __restrict__ in,
                                           const float* __restrict__ w,
                                           const float* __restrict__ b,
                                           bf16* __restrict__ out,
                                           int row, int lane) {
    const float4* xr = (const float4*)(in + (size_t)row * DIM);
    float4 v[4];
    float sum = 0.f, sq = 0.f;
#pragma unroll
    for (int i = 0; i < 4; i++) {
        v[i] = xr[lane + i * 64];
        sum += v[i].x + v[i].y + v[i].z + v[i].w;
        sq  += v[i].x * v[i].x + v[i].y * v[i].y + v[i].z * v[i].z + v[i].w * v[i].w;
    }
#pragma unroll
    for (int off = 32; off >= 1; off >>= 1) {
        sum += __shfl_xor(sum, off);
        sq  += __shfl_xor(sq,  off);
    }
    const float mean = sum * (1.f / DIM);
    const float var  = fmaxf(sq * (1.f / DIM) - mean * mean, 0.f);
    const float rstd = rsqrtf(var + 1e-12f);

    const float4* wv = (const float4*)w;
    const float4* bv = (const float4*)b;
    ushort4* orow = (ushort4*)(out + (size_t)row * DIM);
#pragma unroll
    for (int i = 0; i < 4; i++) {
        const int c = lane + i * 64;
        const float4 wc = wv[c];
        const float4 bc = bv[c];
        ushort4 o;
        o.x = __bfloat16_as_ushort(__float2bfloat16((v[i].x - mean) * rstd * wc.x + bc.x));
        o.y = __bfloat16_as_ushort(__float2bfloat16((v[i].y - mean) * rstd * wc.y + bc.y));
        o.z = __bfloat16_as_ushort(__float2bfloat16((v[i].z - mean) * rstd * wc.z + bc.z));
        o.w = __bfloat16_as_ushort(__float2bfloat16((v[i].w - mean) * rstd * wc.w + bc.w));
        orow[c] = o;
    }
}

__global__ __launch_bounds__(256) void ln_kernel(const float* __restrict__ in,
                                                 const float* __restrict__ w,
                                                 const float* __restrict__ b,
                                                 bf16* __restrict__ out) {
    ln_one_row(in, w, b, out, blockIdx.x * 4 + (threadIdx.x >> 6), threadIdx.x & 63);
}

// ---------------------------------------------------------------------------
// Merged: 5 weight convert+transpose segments + ln1(x) in ONE dispatch.
// blockIdx: [0,3072) qkvw | [3072,4096) attn_ow | [4096,8192) inter_w |
// [8192,12288) inter_w1 | [12288,16384) output_w | [16384,17408) ln1 rows
// ---------------------------------------------------------------------------
__global__ __launch_bounds__(256) void wconv5ln_kernel(
        const float* __restrict__ W0, bf16* __restrict__ T0,
        const float* __restrict__ W1, bf16* __restrict__ T1,
        const float* __restrict__ W2, bf16* __restrict__ T2,
        const float* __restrict__ W3, bf16* __restrict__ T3,
        const float* __restrict__ W4, bf16* __restrict__ T4,
        const float* __restrict__ x, const float* __restrict__ nw,
        const float* __restrict__ nb, bf16* __restrict__ lnout) {
    __shared__ float tile[32][33];
    int bid = blockIdx.x;
    if (bid >= 16384) {
        ln_one_row(x, nw, nb, lnout,
                   (bid - 16384) * 4 + (threadIdx.x >> 6), threadIdx.x & 63);
        return;
    }
    const float* W; bf16* T; int K, N;
    if (bid < 3072)       { W = W0; T = T0; K = 1024; N = 3072; }
    else if (bid < 4096)  { W = W1; T = T1; K = 1024; N = 1024; bid -= 3072; }
    else if (bid < 8192)  { W = W2; T = T2; K = 1024; N = 4096; bid -= 4096; }
    else if (bid < 12288) { W = W3; T = T3; K = 1024; N = 4096; bid -= 8192; }
    else                  { W = W4; T = T4; K = 4096; N = 1024; bid -= 12288; }
    const int ntx = N >> 5;
    const int n0 = (bid % ntx) * 32;
    const int k0 = (bid / ntx) * 32;

    const int tid = threadIdx.x;
    const int c = tid & 31;
    const int r = tid >> 5;           // 0..7
#pragma unroll
    for (int i = 0; i < 4; i++)
        tile[r + i * 8][c] = W[(size_t)(k0 + r + i * 8) * N + n0 + c];
    __syncthreads();
#pragma unroll
    for (int i = 0; i < 4; i++)
        T[(size_t)(n0 + r + i * 8) * K + k0 + c] = __float2bfloat16(tile[c][r + i * 8]);
}

// ---------------------------------------------------------------------------
// MFMA GEMM (counted-vmcnt 2-deep pipeline, v2 ordering):
// iter t: ds_read frags(cur) -> MFMA (compiler's fine-grained lgkmcnt lets
// MFMAs start as soon as their frags land — no forced lgkmcnt(0) drain) ->
// s_barrier (all waves' reads retired) -> refill cur with tile t+2 ->
// vmcnt(L) (tile t+1 landed; refill stays in flight) -> s_barrier.
// 16B-slot XOR swizzle (both-sides rule), XCD-aware block map.
// tile = (TM*32)x(TN*32), BK=32, 4 waves 2x2.
// MODE: 0 = bias(optional) + optional V-transpose scatter (vtout),
//       3 = bias+acc+aux,
//       4 = dual: C (bf16) = acc;  C2 (fp32) = acc + bias2 + xin
// ---------------------------------------------------------------------------
#define GBK 32

template<typename TX, int MODE, int TM, int TN>
__global__ __launch_bounds__(256) void mgemm_kernel(const bf16* __restrict__ A,
                                                    const bf16* __restrict__ Bt,
                                                    const float* __restrict__ bias,
                                                    const TX* __restrict__ aux,
                                                    TX* __restrict__ C,
                                                    const float* __restrict__ bias2,
                                                    const float* __restrict__ xin,
                                                    float* __restrict__ C2,
                                                    bf16* __restrict__ vtout,
                                                    int M, int N, int K) {
    constexpr int TILE_M = TM * 32;
    constexpr int TILE_N = TN * 32;
    constexpr int LOADS  = TM / 2 + TN / 2;   // gload_lds per wave per stage
    __shared__ alignas(16) bf16 As[2][TILE_M][GBK];
    __shared__ alignas(16) bf16 Bs[2][TILE_N][GBK];

    const int tid  = threadIdx.x;
    const int w    = tid >> 6;
    const int lane = tid & 63;
    const int cl   = lane & 15;       // MFMA 16-group
    const int qd   = lane >> 4;       // quad
    const int wm   = w >> 1;
    const int wn   = w & 1;

    int bx, by;
    xcd_map(bx, by);

    const int row0 = by * TILE_M;
    const int col0 = bx * TILE_N;

    const int lrow = lane >> 2;
    const int lkg  = lane & 3;
    const int sslot = lkg ^ ((lrow >> 1) & 3);
    const int rds   = (cl >> 1) & 3;          // read-side swizzle for row cl

    const bf16* gA = A  + (size_t)(row0 + lrow) * K + sslot * 8;
    const bf16* gB = Bt + (size_t)(col0 + lrow) * K + sslot * 8;

    f32x4_t acc[TM][TN];
#pragma unroll
    for (int m = 0; m < TM; m++)
#pragma unroll
        for (int n = 0; n < TN; n++) acc[m][n] = {0.f, 0.f, 0.f, 0.f};

    auto stage = [&](int b, int k0) {
#pragma unroll
        for (int i = 0; i < TM / 2; i++) {
            const int r16 = (w * (TM / 2) + i) * 16;
            gload16(gA + (size_t)r16 * K + k0, &As[b][r16][0]);
        }
#pragma unroll
        for (int j = 0; j < TN / 2; j++) {
            const int r16 = (w * (TN / 2) + j) * 16;
            gload16(gB + (size_t)r16 * K + k0, &Bs[b][r16][0]);
        }
    };

    // prologue: 2 tiles in flight, wait only the first (NT >= 2 always here)
    stage(0, 0);
    stage(1, GBK);
    asm volatile("s_waitcnt vmcnt(%0)" :: "i"(LOADS) : "memory");
    __builtin_amdgcn_s_barrier();

    const int NT = K / GBK;
    for (int t = 0; t < NT; t++) {
        const int cur = t & 1;

        bf16x8_t af[TM], bfr[TN];
#pragma unroll
        for (int m = 0; m < TM; m++)
            af[m] = *(const bf16x8_t*)&As[cur][wm * (TM * 16) + m * 16 + cl][(qd ^ rds) * 8];
#pragma unroll
        for (int n = 0; n < TN; n++)
            bfr[n] = *(const bf16x8_t*)&Bs[cur][wn * (TN * 16) + n * 16 + cl][(qd ^ rds) * 8];

        __builtin_amdgcn_s_setprio(1);
#pragma unroll
        for (int m = 0; m < TM; m++)
#pragma unroll
            for (int n = 0; n < TN; n++)
                acc[m][n] = mfma16(af[m], bfr[n], acc[m][n]);
        __builtin_amdgcn_s_setprio(0);

        if (t + 2 < NT) {
            __builtin_amdgcn_s_barrier();            // all waves' reads of cur retired
            stage(cur, (t + 2) * GBK);               // refill cur
        }
        if (t + 1 < NT) {
            if (t + 2 < NT)
                asm volatile("s_waitcnt vmcnt(%0)" :: "i"(LOADS) : "memory");
            else
                asm volatile("s_waitcnt vmcnt(0)" ::: "memory");
            __builtin_amdgcn_s_barrier();            // buffer t+1 landed on all waves
        }
    }

    // epilogue: C/D layout col=lane&15, row=qd*4+reg
#pragma unroll
    for (int m = 0; m < TM; m++) {
#pragma unroll
        for (int n = 0; n < TN; n++) {
            const int gc = col0 + wn * (TN * 16) + n * 16 + cl;
            const float bv = (MODE != 4 && bias) ? bias[gc] : 0.f;
            const int grb = row0 + wm * (TM * 16) + m * 16 + qd * 4;
            float cv[4];
#pragma unroll
            for (int r = 0; r < 4; r++) {
                float c = acc[m][n][r] + bv;
                if (MODE == 3) c += ldv(aux, (size_t)(grb + r) * N + gc);
                cv[r] = c;
            }
            // V-range of qkv: write transposed into vt[bh][d][s] instead of C
            if (MODE == 0 && vtout != nullptr && gc >= 2 * DIM) {
                const int hv = (gc - 2 * DIM) >> 6;
                const int dv = (gc - 2 * DIM) & 63;
                const int bb = grb >> 11;
                const int sb = grb & 2047;
                ushort4 o;
                o.x = __bfloat16_as_ushort(__float2bfloat16(cv[0]));
                o.y = __bfloat16_as_ushort(__float2bfloat16(cv[1]));
                o.z = __bfloat16_as_ushort(__float2bfloat16(cv[2]));
                o.w = __bfloat16_as_ushort(__float2bfloat16(cv[3]));
                *(ushort4*)(vtout + (((size_t)(bb * NH + hv)) << 17) +
                            ((size_t)dv << 11) + sb) = o;
            } else {
#pragma unroll
                for (int r = 0; r < 4; r++) {
                    stv(C, (size_t)(grb + r) * N + gc, cv[r]);
                    if (MODE == 4)
                        C2[(size_t)(grb + r) * N + gc] =
                            cv[r] + bias2[gc] + xin[(size_t)(grb + r) * N + gc];
                }
            }
        }
    }
}

// ---------------------------------------------------------------------------
// Dual GEMM (fused steps 7+8), wave-split (verified R5/R6), v2 ordering:
// reads -> MFMA (compiler lgkmcnt) -> barrier -> refill -> vmcnt(4) -> barrier.
// 512 thr = 8 waves; waves 0-3 GEMM0 (gelu path), waves 4-7 GEMM1.
// Epilogue joins GEMM1 via LDS fp32 exchange.
// ---------------------------------------------------------------------------
__global__ __launch_bounds__(512, 4) void dualgemm_kernel(const bf16* __restrict__ A0,
                                                          const bf16* __restrict__ B0t,
                                                          const bf16* __restrict__ A1,
                                                          const bf16* __restrict__ B1t,
                                                          const float* __restrict__ bias,
                                                          bf16* __restrict__ C,
                                                          int M, int N, int K) {
    // pool: staging [2 buf][4 arr][128 rows][32 bf16] = 65536 B,
    //       reused after K-loop as fp32 exchange [128][130] = 66560 B
    __shared__ alignas(16) char pool[66560];

    const int tid  = threadIdx.x;
    const int w    = tid >> 6;        // 0..7
    const int lane = tid & 63;
    const int cl   = lane & 15;
    const int qd   = lane >> 4;
    const int gsel = w >> 2;          // 0: GEMM0, 1: GEMM1
    const int g2   = w & 3;
    const int wm   = g2 >> 1;
    const int wn   = g2 & 1;

    int bx, by;
    xcd_map(bx, by);
    const int row0 = by * 128;
    const int col0 = bx * 128;

    const int lrow = lane >> 2;
    const int lkg  = lane & 3;
    const int sslot = lkg ^ ((lrow >> 1) & 3);
    const int rds   = (cl >> 1) & 3;

    // staging: wave w owns array (w>>1) in {A0,B0,A1,B1}, rowgroups (w&1)*4+j
    const int sarr = w >> 1;
    const bf16* gsrc;
    {
        const bf16* bases[4] = {A0, B0t, A1, B1t};
        const int   r0s[4]   = {row0, col0, row0, col0};
        gsrc = bases[sarr] + (size_t)(r0s[sarr] + lrow) * K + sslot * 8;
    }

    auto sptr = [&](int b, int a) -> bf16* {
        return (bf16*)(pool + b * 32768 + a * 8192);
    };

    f32x4_t acc[4][4];
#pragma unroll
    for (int m = 0; m < 4; m++)
#pragma unroll
        for (int n = 0; n < 4; n++) acc[m][n] = {0.f, 0.f, 0.f, 0.f};

    auto stage = [&](int b, int k0) {
        bf16* dst = sptr(b, sarr);
#pragma unroll
        for (int j = 0; j < 4; j++) {
            const int rg = (w & 1) * 4 + j;           // rowgroup 0..7
            gload16(gsrc + (size_t)(rg * 16) * K + k0, dst + rg * 16 * GBK);
        }
    };

    stage(0, 0);
    stage(1, GBK);
    asm volatile("s_waitcnt vmcnt(4)" ::: "memory");
    __builtin_amdgcn_s_barrier();

    const int NT = K / GBK;
    for (int t = 0; t < NT; t++) {
        const int cur = t & 1;
        const bf16* Sa = sptr(cur, gsel * 2);
        const bf16* Sb = sptr(cur, gsel * 2 + 1);

        bf16x8_t af[4], bfr[4];
#pragma unroll
        for (int m = 0; m < 4; m++)
            af[m] = *(const bf16x8_t*)&Sa[(wm * 64 + m * 16 + cl) * GBK + (qd ^ rds) * 8];
#pragma unroll
        for (int n = 0; n < 4; n++)
            bfr[n] = *(const bf16x8_t*)&Sb[(wn * 64 + n * 16 + cl) * GBK + (qd ^ rds) * 8];

        __builtin_amdgcn_s_setprio(1);
#pragma unroll
        for (int m = 0; m < 4; m++)
#pragma unroll
            for (int n = 0; n < 4; n++)
                acc[m][n] = mfma16(af[m], bfr[n], acc[m][n]);
        __builtin_amdgcn_s_setprio(0);

        if (t + 2 < NT) {
            __builtin_amdgcn_s_barrier();            // all waves' reads of cur retired
            stage(cur, (t + 2) * GBK);
        }
        if (t + 1 < NT) {
            if (t + 2 < NT)
                asm volatile("s_waitcnt vmcnt(4)" ::: "memory");
            else
                asm volatile("s_waitcnt vmcnt(0)" ::: "memory");
            __builtin_amdgcn_s_barrier();
        }
    }

    // ---- epilogue: join GEMM1 into GEMM0 through LDS ----
    float* X = (float*)pool;          // [128][130] fp32, staging is dead
    __syncthreads();
    if (gsel == 1) {
#pragma unroll
        for (int m = 0; m < 4; m++)
#pragma unroll
            for (int n = 0; n < 4; n++)
#pragma unroll
                for (int r = 0; r < 4; r++)
                    X[(wm * 64 + m * 16 + qd * 4 + r) * 130 + wn * 64 + n * 16 + cl] =
                        acc[m][n][r];
    }
    __syncthreads();
    if (gsel == 0) {
#pragma unroll
        for (int m = 0; m < 4; m++) {
#pragma unroll
            for (int n = 0; n < 4; n++) {
                const int lc = wn * 64 + n * 16 + cl;
                const int gc = col0 + lc;
                const float bv = bias[gc];
#pragma unroll
                for (int r = 0; r < 4; r++) {
                    const int lr = wm * 64 + m * 16 + qd * 4 + r;
                    float g = acc[m][n][r] + bv;
                    g = 0.5f * g * (1.f + erff(g * 0.70710678118654752f));
                    C[(size_t)(row0 + lr) * N + gc] = __float2bfloat16(g * X[lr * 130 + lc]);
                }
            }
        }
    }
}

// ---------------------------------------------------------------------------
// MFMA flash attention (unchanged; verified).
// ---------------------------------------------------------------------------
#define KCH 64
#define NCH (SEQ / KCH)

__device__ __forceinline__ unsigned pk2(float lo, float hi) {
    unsigned a = (unsigned)__bfloat16_as_ushort(__float2bfloat16(lo));
    unsigned b = (unsigned)__bfloat16_as_ushort(__float2bfloat16(hi));
    return a | (b << 16);
}

union PAU { bf16x8_t v; unsigned u[4]; };

__global__ __launch_bounds__(256, 2) void attn_mfma_kernel(const bf16* __restrict__ qkv,
                                                           const bf16* __restrict__ vt,
                                                           const float* __restrict__ mask,
                                                           bf16* __restrict__ ctx) {
    __shared__ alignas(16) bf16 Kl[2][KCH][64];
    __shared__ alignas(16) bf16 Vl[2][KCH][64];

    const int tid  = threadIdx.x;
    const int w    = tid >> 6;
    const int lane = tid & 63;
    const int cl   = lane & 15;
    const int qd   = lane >> 4;
    const int c7   = cl & 7;

    const int qtile = blockIdx.x;
    const int bh    = blockIdx.y;
    const int bb    = bh >> 4;
    const int h     = bh & 15;

    const bf16*  base = qkv + (size_t)bb * SEQ * (3 * DIM) + h * HD;
    const bf16*  gK   = base + DIM;
    const bf16*  gV   = vt + (size_t)bh * HD * SEQ;
    const float* mrow = mask + (size_t)bb * SEQ;

    bf16x8_t aq[2][2];
#pragma unroll
    for (int qt = 0; qt < 2; qt++) {
        const bf16* qrow = base + (size_t)(qtile * 128 + w * 32 + qt * 16 + cl) * (3 * DIM);
        aq[qt][0] = *(const bf16x8_t*)(qrow + qd * 8);
        aq[qt][1] = *(const bf16x8_t*)(qrow + 32 + qd * 8);
    }

    const bf16x8_t onesv = {0x3F80, 0x3F80, 0x3F80, 0x3F80,
                            0x3F80, 0x3F80, 0x3F80, 0x3F80};

    const int sr  = lane >> 3;
    const int scw = (lane & 7) ^ sr;

#pragma unroll
    for (int i = 0; i < 2; i++) {
        const int row = i * 32 + w * 8 + sr;
        gload16(gK + (size_t)row * (3 * DIM) + scw * 8, &Kl[0][i * 32 + w * 8][0]);
        gload16(gV + (size_t)row * SEQ + scw * 8, &Vl[0][i * 32 + w * 8][0]);
    }
    f32x4_t mkx[4];
#pragma unroll
    for (int ks = 0; ks < 4; ks++)
        mkx[ks] = *(const f32x4_t*)&mrow[ks * 16 + qd * 4];

    f32x4_t O[2][4];
#pragma unroll
    for (int qt = 0; qt < 2; qt++)
#pragma unroll
        for (int ns = 0; ns < 4; ns++) O[qt][ns] = {0.f, 0.f, 0.f, 0.f};
    f32x4_t li[2] = {{0.f,0.f,0.f,0.f},{0.f,0.f,0.f,0.f}};

    for (int c = 0; c < NCH; c++) {
        __syncthreads();
        const bf16 (*Kb)[64] = Kl[c & 1];
        const bf16 (*Vb)[64] = Vl[c & 1];

        f32x4_t mk[4];
#pragma unroll
        for (int ks = 0; ks < 4; ks++) mk[ks] = mkx[ks];

        if (c + 1 < NCH) {
            bf16 (*Kn)[64] = Kl[(c + 1) & 1];
            bf16 (*Vn)[64] = Vl[(c + 1) & 1];
            const int k0n = (c + 1) * KCH;
#pragma unroll
            for (int i = 0; i < 2; i++) {
                const int row = i * 32 + w * 8 + sr;
                gload16(gK + (size_t)(k0n + row) * (3 * DIM) + scw * 8, &Kn[i * 32 + w * 8][0]);
                gload16(gV + (size_t)row * SEQ + k0n + scw * 8, &Vn[i * 32 + w * 8][0]);
            }
#pragma unroll
            for (int ks = 0; ks < 4; ks++)
                mkx[ks] = *(const f32x4_t*)&mrow[k0n + ks * 16 + qd * 4];
        }

        bf16x8_t kf[4][2];
#pragma unroll
        for (int ks = 0; ks < 4; ks++) {
            kf[ks][0] = *(const bf16x8_t*)&Kb[ks * 16 + cl][(qd ^ c7) << 3];
            kf[ks][1] = *(const bf16x8_t*)&Kb[ks * 16 + cl][((4 + qd) ^ c7) << 3];
        }

        PAU pa[2][2];
#pragma unroll
        for (int qt = 0; qt < 2; qt++) {
            unsigned Dv[4][2];
#pragma unroll
            for (int ks = 0; ks < 4; ks++) {
                f32x4_t s = {0.f, 0.f, 0.f, 0.f};
                s = mfma16(kf[ks][0], aq[qt][0], s);
                s = mfma16(kf[ks][1], aq[qt][1], s);
                const float e0 = __expf(s[0] * 0.125f + mk[ks][0]);
                const float e1 = __expf(s[1] * 0.125f + mk[ks][1]);
                const float e2 = __expf(s[2] * 0.125f + mk[ks][2]);
                const float e3 = __expf(s[3] * 0.125f + mk[ks][3]);
                Dv[ks][0] = pk2(e0, e1);
                Dv[ks][1] = pk2(e2, e3);
            }
#pragma unroll
            for (int rp = 0; rp < 2; rp++) {
                auto z0 = __builtin_amdgcn_permlane32_swap(Dv[0][rp], Dv[1][rp], false, false);
                auto w0 = __builtin_amdgcn_permlane16_swap(z0[0], z0[1], false, false);
                pa[qt][0].u[rp]     = w0[0];
                pa[qt][0].u[rp + 2] = w0[1];
                auto z1 = __builtin_amdgcn_permlane32_swap(Dv[2][rp], Dv[3][rp], false, false);
                auto w1 = __builtin_amdgcn_permlane16_swap(z1[0], z1[1], false, false);
                pa[qt][1].u[rp]     = w1[0];
                pa[qt][1].u[rp + 2] = w1[1];
            }
            f32x4_t ls = {0.f, 0.f, 0.f, 0.f};
            ls = mfma16(pa[qt][0].v, onesv, ls);
            ls = mfma16(pa[qt][1].v, onesv, ls);
            li[qt] += ls;
        }

#pragma unroll
        for (int ns = 0; ns < 4; ns++) {
            bf16x8_t v0 = *(const bf16x8_t*)&Vb[ns * 16 + cl][(qd ^ c7) << 3];
            bf16x8_t v1 = *(const bf16x8_t*)&Vb[ns * 16 + cl][((4 + qd) ^ c7) << 3];
#pragma unroll
            for (int qt = 0; qt < 2; qt++) {
                O[qt][ns] = mfma16(pa[qt][0].v, v0, O[qt][ns]);
                O[qt][ns] = mfma16(pa[qt][1].v, v1, O[qt][ns]);
            }
        }
    }

#pragma unroll
    for (int qt = 0; qt < 2; qt++) {
#pragma unroll
        for (int r = 0; r < 4; r++) {
            const int row = qtile * 128 + w * 32 + qt * 16 + qd * 4 + r;
            bf16* orow = ctx + (size_t)(bb * SEQ + row) * DIM + h * HD;
            const float inv = 1.f / li[qt][r];
#pragma unroll
            for (int ns = 0; ns < 4; ns++)
                orow[ns * 16 + cl] = __float2bfloat16(O[qt][ns][r] * inv);
        }
    }
}

// ---------------------------------------------------------------------------
extern "C" void kernel_launch(void* const* d_in, const int* in_sizes, int n_in,
                              void* d_out, int out_size, void* d_ws, size_t ws_size,
                              hipStream_t stream) {
    const float* x        = (const float*)d_in[0];
    const float* mask     = (const float*)d_in[1];
    const float* norm_w   = (const float*)d_in[2];
    const float* norm_b   = (const float*)d_in[3];
    const float* qkvw     = (const float*)d_in[4];
    const float* qkvb     = (const float*)d_in[5];
    const float* attn_ow  = (const float*)d_in[6];
    const float* attn_ob  = (const float*)d_in[7];
    const float* attn_nw  = (const float*)d_in[8];
    const float* attn_nb  = (const float*)d_in[9];
    const float* inter_w  = (const float*)d_in[10];
    const float* inter_b  = (const float*)d_in[11];
    const float* inter_w1 = (const float*)d_in[12];
    const float* output_w = (const float*)d_in[13];
    const float* output_b = (const float*)d_in[14];

    float* out = (float*)d_out;
    bf16*  ws  = (bf16*)d_ws;

    const size_t M1 = 1024 * 1024;
    // ws layout (bf16 elems), peak 36M = 72 MB. Liveness-checked overlaps:
    //  [0,4M)    ln1 / ctx / ln2
    //  [4M,16M)  qkv (steps 2-3); [4M,20M) inter (steps 7-9)
    //  [16M,19M) qkvw_t  (steps 0-2; inside inter region, dead before step 7)
    //  [19M,20M) attn_owt (steps 0-4; same)
    //  [20M,24M) Vt (steps 2-3b) then attn_out (steps 4-8) — Vt dead at 4
    //  [24M,28M) inter_w_t  [28M,32M) inter_w1_t  [32M,36M) output_w_t
    bf16* ln_s      = ws;
    bf16* qkv       = ws + 4 * M1;
    bf16* inter     = ws + 4 * M1;
    bf16* qkvw_t    = ws + 16 * M1;
    bf16* attn_owt  = ws + 19 * M1;
    bf16* vt        = ws + 20 * M1;
    bf16* attn_out  = ws + 20 * M1;
    bf16* inter_wt  = ws + 24 * M1;
    bf16* inter_w1t = ws + 28 * M1;
    bf16* output_wt = ws + 32 * M1;
    float* resid    = out;

    dim3 blk(256);
    dim3 blk512(512);

    // 0+1. merged weight convert+transpose (5 segments) + ln1(x), 1 launch
    wconv5ln_kernel<<<dim3(16384 + TOK / 4), blk, 0, stream>>>(
        qkvw, qkvw_t, attn_ow, attn_owt, inter_w, inter_wt,
        inter_w1, inter_w1t, output_w, output_wt,
        x, norm_w, norm_b, ln_s);

    // 2. qkv = ln1 @ qkvw + qkvb  [4096, 3072]; V-range written transposed
    //    into vt[bh][d][s] directly (qkv V-slice store skipped — dead).
    mgemm_kernel<bf16, 0, 4, 4><<<dim3(3072 / 128, TOK / 128), blk, 0, stream>>>(
        ln_s, qkvw_t, qkvb, (const bf16*)nullptr, qkv,
        nullptr, nullptr, nullptr, vt, TOK, 3 * DIM, DIM);

    // 3. MFMA flash attention -> ctx (reuses ln slot)
    attn_mfma_kernel<<<dim3(SEQ / 128, BATCH * NH), blk, 0, stream>>>(qkv, vt, mask, ln_s);

    // 4+5. attn_out = ctx @ attn_ow (no bias); resid = attn_out + attn_ob + x
    mgemm_kernel<bf16, 4, 4, 2><<<dim3(DIM / 64, TOK / 128), blk, 0, stream>>>(
        ln_s, attn_owt, (const float*)nullptr, (const bf16*)nullptr, attn_out,
        attn_ob, x, resid, nullptr, TOK, DIM, DIM);

    // 6. ln2 = LN(resid)
    ln_kernel<<<TOK / 4, blk, 0, stream>>>(resid, attn_nw, attn_nb, ln_s);

    // 7+8 fused. inter = gelu(ln2 @ inter_w + inter_b) * (attn_out @ inter_w1)
    dualgemm_kernel<<<dim3(IDIM / 128, TOK / 128), blk512, 0, stream>>>(
        ln_s, inter_wt, attn_out, inter_w1t, inter_b, inter, TOK, IDIM, DIM);

    // 9. out = inter @ output_w + output_b + resid  (K=4096, N=1024)
    mgemm_kernel<float, 3, 4, 2><<<dim3(DIM / 64, TOK / 128), blk, 0, stream>>>(
        inter, output_wt, output_b, resid, out,
        nullptr, nullptr, nullptr, nullptr, TOK, DIM, IDIM);
}

// Round 10
// 434.309 us; speedup vs baseline: 1.0402x; 1.0402x over previous
//
#include <hip/hip_runtime.h>
#include <hip/hip_bf16.h>

// Problem dims (fixed by reference)
#define BATCH 2
#define SEQ   2048
#define DIM   1024
#define IDIM  4096
#define NH    16
#define HD    64
#define TOK   (BATCH * SEQ)      // 4096 token rows

typedef __hip_bfloat16 bf16;

typedef short bf16x8_t __attribute__((ext_vector_type(8)));
typedef float f32x4_t  __attribute__((ext_vector_type(4)));

__device__ __forceinline__ float ldv(const float* p, size_t i) { return p[i]; }
__device__ __forceinline__ float ldv(const bf16*  p, size_t i) { return __bfloat162float(p[i]); }
__device__ __forceinline__ void  stv(float* p, size_t i, float v) { p[i] = v; }
__device__ __forceinline__ void  stv(bf16*  p, size_t i, float v) { p[i] = __float2bfloat16(v); }

__device__ __forceinline__ f32x4_t mfma16(bf16x8_t a, bf16x8_t b, f32x4_t c) {
    return __builtin_amdgcn_mfma_f32_16x16x32_bf16(a, b, c, 0, 0, 0);
}

// async global->LDS, 16B per lane; LDS dest = wave-uniform base + lane*16
__device__ __forceinline__ void gload16(const bf16* g, bf16* l) {
    __builtin_amdgcn_global_load_lds(
        (const __attribute__((address_space(1))) void*)g,
        (__attribute__((address_space(3))) void*)l, 16, 0, 0);
}

// XCD-aware block mapping (verified: cut dualgemm FETCH 277->98.6 MB).
__device__ __forceinline__ void xcd_map(int &bx, int &by) {
    const int gn  = gridDim.x;
    const int lin = blockIdx.y * gn + blockIdx.x;
    const int cx  = gn >> 3;
    const int xcd = lin & 7;
    const int slot = lin >> 3;
    bx = xcd * cx + slot % cx;
    by = slot / cx;
}

// ---------------------------------------------------------------------------
// LayerNorm row (1 wave per row): float4 loads, shfl_xor reduce, ushort4 out.
// ---------------------------------------------------------------------------
__device__ __forceinline__ void ln_one_row(const float* __restrict__ in,
                                           const float* __restrict__ w,
                                           const float* __restrict__ b,
                                           bf16* __restrict__ out,
                                           int row, int lane) {
    const float4* xr = (const float4*)(in + (size_t)row * DIM);
    float4 v[4];
    float sum = 0.f, sq = 0.f;
#pragma unroll
    for (int i = 0; i < 4; i++) {
        v[i] = xr[lane + i * 64];
        sum += v[i].x + v[i].y + v[i].z + v[i].w;
        sq  += v[i].x * v[i].x + v[i].y * v[i].y + v[i].z * v[i].z + v[i].w * v[i].w;
    }
#pragma unroll
    for (int off = 32; off >= 1; off >>= 1) {
        sum += __shfl_xor(sum, off);
        sq  += __shfl_xor(sq,  off);
    }
    const float mean = sum * (1.f / DIM);
    const float var  = fmaxf(sq * (1.f / DIM) - mean * mean, 0.f);
    const float rstd = rsqrtf(var + 1e-12f);

    const float4* wv = (const float4*)w;
    const float4* bv = (const float4*)b;
    ushort4* orow = (ushort4*)(out + (size_t)row * DIM);
#pragma unroll
    for (int i = 0; i < 4; i++) {
        const int c = lane + i * 64;
        const float4 wc = wv[c];
        const float4 bc = bv[c];
        ushort4 o;
        o.x = __bfloat16_as_ushort(__float2bfloat16((v[i].x - mean) * rstd * wc.x + bc.x));
        o.y = __bfloat16_as_ushort(__float2bfloat16((v[i].y - mean) * rstd * wc.y + bc.y));
        o.z = __bfloat16_as_ushort(__float2bfloat16((v[i].z - mean) * rstd * wc.z + bc.z));
        o.w = __bfloat16_as_ushort(__float2bfloat16((v[i].w - mean) * rstd * wc.w + bc.w));
        orow[c] = o;
    }
}

__global__ __launch_bounds__(256) void ln_kernel(const float* __restrict__ in,
                                                 const float* __restrict__ w,
                                                 const float* __restrict__ b,
                                                 bf16* __restrict__ out) {
    ln_one_row(in, w, b, out, blockIdx.x * 4 + (threadIdx.x >> 6), threadIdx.x & 63);
}

// ---------------------------------------------------------------------------
// Merged: 5 weight convert+transpose segments + ln1(x) in ONE dispatch.
// blockIdx: [0,3072) qkvw | [3072,4096) attn_ow | [4096,8192) inter_w |
// [8192,12288) inter_w1 | [12288,16384) output_w | [16384,17408) ln1 rows
// ---------------------------------------------------------------------------
__global__ __launch_bounds__(256) void wconv5ln_kernel(
        const float* __restrict__ W0, bf16* __restrict__ T0,
        const float* __restrict__ W1, bf16* __restrict__ T1,
        const float* __restrict__ W2, bf16* __restrict__ T2,
        const float* __restrict__ W3, bf16* __restrict__ T3,
        const float* __restrict__ W4, bf16* __restrict__ T4,
        const float* __restrict__ x, const float* __restrict__ nw,
        const float* __restrict__ nb, bf16* __restrict__ lnout) {
    __shared__ float tile[32][33];
    int bid = blockIdx.x;
    if (bid >= 16384) {
        ln_one_row(x, nw, nb, lnout,
                   (bid - 16384) * 4 + (threadIdx.x >> 6), threadIdx.x & 63);
        return;
    }
    const float* W; bf16* T; int K, N;
    if (bid < 3072)       { W = W0; T = T0; K = 1024; N = 3072; }
    else if (bid < 4096)  { W = W1; T = T1; K = 1024; N = 1024; bid -= 3072; }
    else if (bid < 8192)  { W = W2; T = T2; K = 1024; N = 4096; bid -= 4096; }
    else if (bid < 12288) { W = W3; T = T3; K = 1024; N = 4096; bid -= 8192; }
    else                  { W = W4; T = T4; K = 4096; N = 1024; bid -= 12288; }
    const int ntx = N >> 5;
    const int n0 = (bid % ntx) * 32;
    const int k0 = (bid / ntx) * 32;

    const int tid = threadIdx.x;
    const int c = tid & 31;
    const int r = tid >> 5;           // 0..7
#pragma unroll
    for (int i = 0; i < 4; i++)
        tile[r + i * 8][c] = W[(size_t)(k0 + r + i * 8) * N + n0 + c];
    __syncthreads();
#pragma unroll
    for (int i = 0; i < 4; i++)
        T[(size_t)(n0 + r + i * 8) * K + k0 + c] = __float2bfloat16(tile[c][r + i * 8]);
}

// ---------------------------------------------------------------------------
// MFMA GEMM (R8 best-measured config, 256 thr): counted-vmcnt 2-deep
// pipeline, v1 ordering. Per iter: ds_read frags(cur) -> lgkmcnt(0)+
// sched_barrier -> s_barrier -> refill cur with tile t+2 -> MFMA (setprio)
// -> vmcnt(L) -> s_barrier. 16B-slot XOR swizzle (both-sides rule),
// XCD-aware block map. tile = (TM*32)x(TN*32), BK=32, 4 waves 2x2.
// MODE: 0 = bias(optional), 3 = bias+acc+aux,
//       4 = dual: C (bf16) = acc;  C2 (fp32) = acc + bias2 + xin
// ---------------------------------------------------------------------------
#define GBK 32

template<typename TX, int MODE, int TM, int TN>
__global__ __launch_bounds__(256) void mgemm_kernel(const bf16* __restrict__ A,
                                                    const bf16* __restrict__ Bt,
                                                    const float* __restrict__ bias,
                                                    const TX* __restrict__ aux,
                                                    TX* __restrict__ C,
                                                    const float* __restrict__ bias2,
                                                    const float* __restrict__ xin,
                                                    float* __restrict__ C2,
                                                    int M, int N, int K) {
    constexpr int TILE_M = TM * 32;
    constexpr int TILE_N = TN * 32;
    constexpr int LOADS  = TM / 2 + TN / 2;   // gload_lds per wave per stage
    __shared__ alignas(16) bf16 As[2][TILE_M][GBK];
    __shared__ alignas(16) bf16 Bs[2][TILE_N][GBK];

    const int tid  = threadIdx.x;
    const int w    = tid >> 6;
    const int lane = tid & 63;
    const int cl   = lane & 15;       // MFMA 16-group
    const int qd   = lane >> 4;       // quad
    const int wm   = w >> 1;
    const int wn   = w & 1;

    int bx, by;
    xcd_map(bx, by);

    const int row0 = by * TILE_M;
    const int col0 = bx * TILE_N;

    const int lrow = lane >> 2;
    const int lkg  = lane & 3;
    const int sslot = lkg ^ ((lrow >> 1) & 3);
    const int rds   = (cl >> 1) & 3;          // read-side swizzle for row cl

    const bf16* gA = A  + (size_t)(row0 + lrow) * K + sslot * 8;
    const bf16* gB = Bt + (size_t)(col0 + lrow) * K + sslot * 8;

    f32x4_t acc[TM][TN];
#pragma unroll
    for (int m = 0; m < TM; m++)
#pragma unroll
        for (int n = 0; n < TN; n++) acc[m][n] = {0.f, 0.f, 0.f, 0.f};

    auto stage = [&](int b, int k0) {
#pragma unroll
        for (int i = 0; i < TM / 2; i++) {
            const int r16 = (w * (TM / 2) + i) * 16;
            gload16(gA + (size_t)r16 * K + k0, &As[b][r16][0]);
        }
#pragma unroll
        for (int j = 0; j < TN / 2; j++) {
            const int r16 = (w * (TN / 2) + j) * 16;
            gload16(gB + (size_t)r16 * K + k0, &Bs[b][r16][0]);
        }
    };

    // prologue: 2 tiles in flight, wait only the first (NT >= 2 always here)
    stage(0, 0);
    stage(1, GBK);
    asm volatile("s_waitcnt vmcnt(%0)" :: "i"(LOADS) : "memory");
    __builtin_amdgcn_s_barrier();

    const int NT = K / GBK;
    for (int t = 0; t < NT; t++) {
        const int cur = t & 1;

        bf16x8_t af[TM], bfr[TN];
#pragma unroll
        for (int m = 0; m < TM; m++)
            af[m] = *(const bf16x8_t*)&As[cur][wm * (TM * 16) + m * 16 + cl][(qd ^ rds) * 8];
#pragma unroll
        for (int n = 0; n < TN; n++)
            bfr[n] = *(const bf16x8_t*)&Bs[cur][wn * (TN * 16) + n * 16 + cl][(qd ^ rds) * 8];
        asm volatile("s_waitcnt lgkmcnt(0)" ::: "memory");
        __builtin_amdgcn_sched_barrier(0);
        __builtin_amdgcn_s_barrier();     // all waves' reads of cur retired

        if (t + 2 < NT) stage(cur, (t + 2) * GBK);   // refill cur (safe now)

        __builtin_amdgcn_s_setprio(1);
#pragma unroll
        for (int m = 0; m < TM; m++)
#pragma unroll
            for (int n = 0; n < TN; n++)
                acc[m][n] = mfma16(af[m], bfr[n], acc[m][n]);
        __builtin_amdgcn_s_setprio(0);

        if (t + 1 < NT) {
            if (t + 2 < NT)
                asm volatile("s_waitcnt vmcnt(%0)" :: "i"(LOADS) : "memory");
            else
                asm volatile("s_waitcnt vmcnt(0)" ::: "memory");
            __builtin_amdgcn_s_barrier(); // buffer t+1 landed on all waves
        }
    }

    // epilogue: C/D layout col=lane&15, row=qd*4+reg
#pragma unroll
    for (int m = 0; m < TM; m++) {
#pragma unroll
        for (int n = 0; n < TN; n++) {
            const int gc = col0 + wn * (TN * 16) + n * 16 + cl;
            const float bv = (MODE != 4 && bias) ? bias[gc] : 0.f;
#pragma unroll
            for (int r = 0; r < 4; r++) {
                const int gr = row0 + wm * (TM * 16) + m * 16 + qd * 4 + r;
                float c = acc[m][n][r] + bv;
                if (MODE == 3) {
                    c += ldv(aux, (size_t)gr * N + gc);
                }
                stv(C, (size_t)gr * N + gc, c);
                if (MODE == 4) {
                    C2[(size_t)gr * N + gc] = c + bias2[gc] + xin[(size_t)gr * N + gc];
                }
            }
        }
    }
}

// ---------------------------------------------------------------------------
// Dual GEMM (fused steps 7+8), wave-split (verified R5/R9: 105 us, occ 33%).
// 512 thr = 8 waves; waves 0-3 GEMM0 (gelu path), waves 4-7 GEMM1.
// Counted-vmcnt schedule (v1 ordering); epilogue joins GEMM1 via LDS fp32
// exchange.
// ---------------------------------------------------------------------------
__global__ __launch_bounds__(512, 4) void dualgemm_kernel(const bf16* __restrict__ A0,
                                                          const bf16* __restrict__ B0t,
                                                          const bf16* __restrict__ A1,
                                                          const bf16* __restrict__ B1t,
                                                          const float* __restrict__ bias,
                                                          bf16* __restrict__ C,
                                                          int M, int N, int K) {
    // pool: staging [2 buf][4 arr][128 rows][32 bf16] = 65536 B,
    //       reused after K-loop as fp32 exchange [128][130] = 66560 B
    __shared__ alignas(16) char pool[66560];

    const int tid  = threadIdx.x;
    const int w    = tid >> 6;        // 0..7
    const int lane = tid & 63;
    const int cl   = lane & 15;
    const int qd   = lane >> 4;
    const int gsel = w >> 2;          // 0: GEMM0, 1: GEMM1
    const int g2   = w & 3;
    const int wm   = g2 >> 1;
    const int wn   = g2 & 1;

    int bx, by;
    xcd_map(bx, by);
    const int row0 = by * 128;
    const int col0 = bx * 128;

    const int lrow = lane >> 2;
    const int lkg  = lane & 3;
    const int sslot = lkg ^ ((lrow >> 1) & 3);
    const int rds   = (cl >> 1) & 3;

    // staging: wave w owns array (w>>1) in {A0,B0,A1,B1}, rowgroups (w&1)*4+j
    const int sarr = w >> 1;
    const bf16* gsrc;
    {
        const bf16* bases[4] = {A0, B0t, A1, B1t};
        const int   r0s[4]   = {row0, col0, row0, col0};
        gsrc = bases[sarr] + (size_t)(r0s[sarr] + lrow) * K + sslot * 8;
    }

    auto sptr = [&](int b, int a) -> bf16* {
        return (bf16*)(pool + b * 32768 + a * 8192);
    };

    f32x4_t acc[4][4];
#pragma unroll
    for (int m = 0; m < 4; m++)
#pragma unroll
        for (int n = 0; n < 4; n++) acc[m][n] = {0.f, 0.f, 0.f, 0.f};

    auto stage = [&](int b, int k0) {
        bf16* dst = sptr(b, sarr);
#pragma unroll
        for (int j = 0; j < 4; j++) {
            const int rg = (w & 1) * 4 + j;           // rowgroup 0..7
            gload16(gsrc + (size_t)(rg * 16) * K + k0, dst + rg * 16 * GBK);
        }
    };

    stage(0, 0);
    stage(1, GBK);
    asm volatile("s_waitcnt vmcnt(4)" ::: "memory");
    __builtin_amdgcn_s_barrier();

    const int NT = K / GBK;
    for (int t = 0; t < NT; t++) {
        const int cur = t & 1;
        const bf16* Sa = sptr(cur, gsel * 2);
        const bf16* Sb = sptr(cur, gsel * 2 + 1);

        bf16x8_t af[4], bfr[4];
#pragma unroll
        for (int m = 0; m < 4; m++)
            af[m] = *(const bf16x8_t*)&Sa[(wm * 64 + m * 16 + cl) * GBK + (qd ^ rds) * 8];
#pragma unroll
        for (int n = 0; n < 4; n++)
            bfr[n] = *(const bf16x8_t*)&Sb[(wn * 64 + n * 16 + cl) * GBK + (qd ^ rds) * 8];
        asm volatile("s_waitcnt lgkmcnt(0)" ::: "memory");
        __builtin_amdgcn_sched_barrier(0);
        __builtin_amdgcn_s_barrier();     // all waves' reads of cur retired

        if (t + 2 < NT) stage(cur, (t + 2) * GBK);

        __builtin_amdgcn_s_setprio(1);
#pragma unroll
        for (int m = 0; m < 4; m++)
#pragma unroll
            for (int n = 0; n < 4; n++)
                acc[m][n] = mfma16(af[m], bfr[n], acc[m][n]);
        __builtin_amdgcn_s_setprio(0);

        if (t + 1 < NT) {
            if (t + 2 < NT)
                asm volatile("s_waitcnt vmcnt(4)" ::: "memory");
            else
                asm volatile("s_waitcnt vmcnt(0)" ::: "memory");
            __builtin_amdgcn_s_barrier();
        }
    }

    // ---- epilogue: join GEMM1 into GEMM0 through LDS ----
    float* X = (float*)pool;          // [128][130] fp32, staging is dead
    __syncthreads();
    if (gsel == 1) {
#pragma unroll
        for (int m = 0; m < 4; m++)
#pragma unroll
            for (int n = 0; n < 4; n++)
#pragma unroll
                for (int r = 0; r < 4; r++)
                    X[(wm * 64 + m * 16 + qd * 4 + r) * 130 + wn * 64 + n * 16 + cl] =
                        acc[m][n][r];
    }
    __syncthreads();
    if (gsel == 0) {
#pragma unroll
        for (int m = 0; m < 4; m++) {
#pragma unroll
            for (int n = 0; n < 4; n++) {
                const int lc = wn * 64 + n * 16 + cl;
                const int gc = col0 + lc;
                const float bv = bias[gc];
#pragma unroll
                for (int r = 0; r < 4; r++) {
                    const int lr = wm * 64 + m * 16 + qd * 4 + r;
                    float g = acc[m][n][r] + bv;
                    g = 0.5f * g * (1.f + erff(g * 0.70710678118654752f));
                    C[(size_t)(row0 + lr) * N + gc] = __float2bfloat16(g * X[lr * 130 + lc]);
                }
            }
        }
    }
}

// ---------------------------------------------------------------------------
// V pre-transpose for attention: qkv V-slice [s][d] -> Vt[bh][d][s] (bf16).
// ---------------------------------------------------------------------------
__global__ __launch_bounds__(256) void vtrans_kernel(const bf16* __restrict__ qkv,
                                                     bf16* __restrict__ vt) {
    __shared__ bf16 t[64][72];
    const int tid = threadIdx.x;
    const int s0  = blockIdx.x * 64;
    const int bh  = blockIdx.y;
    const int bb  = bh >> 4;
    const int h   = bh & 15;
    const bf16* src = qkv + (size_t)bb * SEQ * (3 * DIM) + 2 * DIM + h * HD;
    const int r  = tid >> 3;
    const int cc = tid & 7;
#pragma unroll
    for (int i = 0; i < 2; i++)
        *(bf16x8_t*)&t[r + i * 32][cc * 8] =
            *(const bf16x8_t*)(src + (size_t)(s0 + r + i * 32) * (3 * DIM) + cc * 8);
    __syncthreads();
    bf16* dst = vt + (size_t)bh * HD * SEQ + s0;
#pragma unroll
    for (int i = 0; i < 2; i++) {
        const int d = r + i * 32;
        bf16x8_t v;
#pragma unroll
        for (int j = 0; j < 8; j++)
            ((short*)&v)[j] = *(const short*)&t[cc * 8 + j][d];
        *(bf16x8_t*)(dst + (size_t)d * SEQ + cc * 8) = v;
    }
}

// ---------------------------------------------------------------------------
// MFMA flash attention (unchanged; verified).
// ---------------------------------------------------------------------------
#define KCH 64
#define NCH (SEQ / KCH)

__device__ __forceinline__ unsigned pk2(float lo, float hi) {
    unsigned a = (unsigned)__bfloat16_as_ushort(__float2bfloat16(lo));
    unsigned b = (unsigned)__bfloat16_as_ushort(__float2bfloat16(hi));
    return a | (b << 16);
}

union PAU { bf16x8_t v; unsigned u[4]; };

__global__ __launch_bounds__(256, 2) void attn_mfma_kernel(const bf16* __restrict__ qkv,
                                                           const bf16* __restrict__ vt,
                                                           const float* __restrict__ mask,
                                                           bf16* __restrict__ ctx) {
    __shared__ alignas(16) bf16 Kl[2][KCH][64];
    __shared__ alignas(16) bf16 Vl[2][KCH][64];

    const int tid  = threadIdx.x;
    const int w    = tid >> 6;
    const int lane = tid & 63;
    const int cl   = lane & 15;
    const int qd   = lane >> 4;
    const int c7   = cl & 7;

    const int qtile = blockIdx.x;
    const int bh    = blockIdx.y;
    const int bb    = bh >> 4;
    const int h     = bh & 15;

    const bf16*  base = qkv + (size_t)bb * SEQ * (3 * DIM) + h * HD;
    const bf16*  gK   = base + DIM;
    const bf16*  gV   = vt + (size_t)bh * HD * SEQ;
    const float* mrow = mask + (size_t)bb * SEQ;

    bf16x8_t aq[2][2];
#pragma unroll
    for (int qt = 0; qt < 2; qt++) {
        const bf16* qrow = base + (size_t)(qtile * 128 + w * 32 + qt * 16 + cl) * (3 * DIM);
        aq[qt][0] = *(const bf16x8_t*)(qrow + qd * 8);
        aq[qt][1] = *(const bf16x8_t*)(qrow + 32 + qd * 8);
    }

    const bf16x8_t onesv = {0x3F80, 0x3F80, 0x3F80, 0x3F80,
                            0x3F80, 0x3F80, 0x3F80, 0x3F80};

    const int sr  = lane >> 3;
    const int scw = (lane & 7) ^ sr;

#pragma unroll
    for (int i = 0; i < 2; i++) {
        const int row = i * 32 + w * 8 + sr;
        gload16(gK + (size_t)row * (3 * DIM) + scw * 8, &Kl[0][i * 32 + w * 8][0]);
        gload16(gV + (size_t)row * SEQ + scw * 8, &Vl[0][i * 32 + w * 8][0]);
    }
    f32x4_t mkx[4];
#pragma unroll
    for (int ks = 0; ks < 4; ks++)
        mkx[ks] = *(const f32x4_t*)&mrow[ks * 16 + qd * 4];

    f32x4_t O[2][4];
#pragma unroll
    for (int qt = 0; qt < 2; qt++)
#pragma unroll
        for (int ns = 0; ns < 4; ns++) O[qt][ns] = {0.f, 0.f, 0.f, 0.f};
    f32x4_t li[2] = {{0.f,0.f,0.f,0.f},{0.f,0.f,0.f,0.f}};

    for (int c = 0; c < NCH; c++) {
        __syncthreads();
        const bf16 (*Kb)[64] = Kl[c & 1];
        const bf16 (*Vb)[64] = Vl[c & 1];

        f32x4_t mk[4];
#pragma unroll
        for (int ks = 0; ks < 4; ks++) mk[ks] = mkx[ks];

        if (c + 1 < NCH) {
            bf16 (*Kn)[64] = Kl[(c + 1) & 1];
            bf16 (*Vn)[64] = Vl[(c + 1) & 1];
            const int k0n = (c + 1) * KCH;
#pragma unroll
            for (int i = 0; i < 2; i++) {
                const int row = i * 32 + w * 8 + sr;
                gload16(gK + (size_t)(k0n + row) * (3 * DIM) + scw * 8, &Kn[i * 32 + w * 8][0]);
                gload16(gV + (size_t)row * SEQ + k0n + scw * 8, &Vn[i * 32 + w * 8][0]);
            }
#pragma unroll
            for (int ks = 0; ks < 4; ks++)
                mkx[ks] = *(const f32x4_t*)&mrow[k0n + ks * 16 + qd * 4];
        }

        bf16x8_t kf[4][2];
#pragma unroll
        for (int ks = 0; ks < 4; ks++) {
            kf[ks][0] = *(const bf16x8_t*)&Kb[ks * 16 + cl][(qd ^ c7) << 3];
            kf[ks][1] = *(const bf16x8_t*)&Kb[ks * 16 + cl][((4 + qd) ^ c7) << 3];
        }

        PAU pa[2][2];
#pragma unroll
        for (int qt = 0; qt < 2; qt++) {
            unsigned Dv[4][2];
#pragma unroll
            for (int ks = 0; ks < 4; ks++) {
                f32x4_t s = {0.f, 0.f, 0.f, 0.f};
                s = mfma16(kf[ks][0], aq[qt][0], s);
                s = mfma16(kf[ks][1], aq[qt][1], s);
                const float e0 = __expf(s[0] * 0.125f + mk[ks][0]);
                const float e1 = __expf(s[1] * 0.125f + mk[ks][1]);
                const float e2 = __expf(s[2] * 0.125f + mk[ks][2]);
                const float e3 = __expf(s[3] * 0.125f + mk[ks][3]);
                Dv[ks][0] = pk2(e0, e1);
                Dv[ks][1] = pk2(e2, e3);
            }
#pragma unroll
            for (int rp = 0; rp < 2; rp++) {
                auto z0 = __builtin_amdgcn_permlane32_swap(Dv[0][rp], Dv[1][rp], false, false);
                auto w0 = __builtin_amdgcn_permlane16_swap(z0[0], z0[1], false, false);
                pa[qt][0].u[rp]     = w0[0];
                pa[qt][0].u[rp + 2] = w0[1];
                auto z1 = __builtin_amdgcn_permlane32_swap(Dv[2][rp], Dv[3][rp], false, false);
                auto w1 = __builtin_amdgcn_permlane16_swap(z1[0], z1[1], false, false);
                pa[qt][1].u[rp]     = w1[0];
                pa[qt][1].u[rp + 2] = w1[1];
            }
            f32x4_t ls = {0.f, 0.f, 0.f, 0.f};
            ls = mfma16(pa[qt][0].v, onesv, ls);
            ls = mfma16(pa[qt][1].v, onesv, ls);
            li[qt] += ls;
        }

#pragma unroll
        for (int ns = 0; ns < 4; ns++) {
            bf16x8_t v0 = *(const bf16x8_t*)&Vb[ns * 16 + cl][(qd ^ c7) << 3];
            bf16x8_t v1 = *(const bf16x8_t*)&Vb[ns * 16 + cl][((4 + qd) ^ c7) << 3];
#pragma unroll
            for (int qt = 0; qt < 2; qt++) {
                O[qt][ns] = mfma16(pa[qt][0].v, v0, O[qt][ns]);
                O[qt][ns] = mfma16(pa[qt][1].v, v1, O[qt][ns]);
            }
        }
    }

#pragma unroll
    for (int qt = 0; qt < 2; qt++) {
#pragma unroll
        for (int r = 0; r < 4; r++) {
            const int row = qtile * 128 + w * 32 + qt * 16 + qd * 4 + r;
            bf16* orow = ctx + (size_t)(bb * SEQ + row) * DIM + h * HD;
            const float inv = 1.f / li[qt][r];
#pragma unroll
            for (int ns = 0; ns < 4; ns++)
                orow[ns * 16 + cl] = __float2bfloat16(O[qt][ns][r] * inv);
        }
    }
}

// ---------------------------------------------------------------------------
extern "C" void kernel_launch(void* const* d_in, const int* in_sizes, int n_in,
                              void* d_out, int out_size, void* d_ws, size_t ws_size,
                              hipStream_t stream) {
    const float* x        = (const float*)d_in[0];
    const float* mask     = (const float*)d_in[1];
    const float* norm_w   = (const float*)d_in[2];
    const float* norm_b   = (const float*)d_in[3];
    const float* qkvw     = (const float*)d_in[4];
    const float* qkvb     = (const float*)d_in[5];
    const float* attn_ow  = (const float*)d_in[6];
    const float* attn_ob  = (const float*)d_in[7];
    const float* attn_nw  = (const float*)d_in[8];
    const float* attn_nb  = (const float*)d_in[9];
    const float* inter_w  = (const float*)d_in[10];
    const float* inter_b  = (const float*)d_in[11];
    const float* inter_w1 = (const float*)d_in[12];
    const float* output_w = (const float*)d_in[13];
    const float* output_b = (const float*)d_in[14];

    float* out = (float*)d_out;
    bf16*  ws  = (bf16*)d_ws;

    const size_t M1 = 1024 * 1024;
    // ws layout (bf16 elems), peak 36M = 72 MB. Liveness-checked overlaps:
    //  [0,4M)    ln1 / ctx / ln2
    //  [4M,16M)  qkv (steps 2-3); [4M,20M) inter (steps 7-9)
    //  [16M,19M) qkvw_t  (steps 0-2; inside inter region, dead before step 7)
    //  [19M,20M) attn_owt (steps 0-4; same)
    //  [20M,24M) Vt (steps 3a-3b) then attn_out (steps 4-8) — Vt dead at 4
    //  [24M,28M) inter_w_t  [28M,32M) inter_w1_t  [32M,36M) output_w_t
    bf16* ln_s      = ws;
    bf16* qkv       = ws + 4 * M1;
    bf16* inter     = ws + 4 * M1;
    bf16* qkvw_t    = ws + 16 * M1;
    bf16* attn_owt  = ws + 19 * M1;
    bf16* vt        = ws + 20 * M1;
    bf16* attn_out  = ws + 20 * M1;
    bf16* inter_wt  = ws + 24 * M1;
    bf16* inter_w1t = ws + 28 * M1;
    bf16* output_wt = ws + 32 * M1;
    float* resid    = out;

    dim3 blk(256);
    dim3 blk512(512);

    // 0+1. merged weight convert+transpose (5 segments) + ln1(x), 1 launch
    wconv5ln_kernel<<<dim3(16384 + TOK / 4), blk, 0, stream>>>(
        qkvw, qkvw_t, attn_ow, attn_owt, inter_w, inter_wt,
        inter_w1, inter_w1t, output_w, output_wt,
        x, norm_w, norm_b, ln_s);

    // 2. qkv = ln1 @ qkvw + qkvb     [4096, 3072]  (24x32 = 768 blocks)
    mgemm_kernel<bf16, 0, 4, 4><<<dim3(3072 / 128, TOK / 128), blk, 0, stream>>>(
        ln_s, qkvw_t, qkvb, (const bf16*)nullptr, qkv,
        nullptr, nullptr, nullptr, TOK, 3 * DIM, DIM);

    // 3a. V pre-transpose -> Vt[bh][d][s]
    vtrans_kernel<<<dim3(SEQ / 64, BATCH * NH), blk, 0, stream>>>(qkv, vt);

    // 3b. MFMA flash attention -> ctx (reuses ln slot)
    attn_mfma_kernel<<<dim3(SEQ / 128, BATCH * NH), blk, 0, stream>>>(qkv, vt, mask, ln_s);

    // 4+5. attn_out = ctx @ attn_ow (no bias); resid = attn_out + attn_ob + x
    mgemm_kernel<bf16, 4, 4, 2><<<dim3(DIM / 64, TOK / 128), blk, 0, stream>>>(
        ln_s, attn_owt, (const float*)nullptr, (const bf16*)nullptr, attn_out,
        attn_ob, x, resid, TOK, DIM, DIM);

    // 6. ln2 = LN(resid)
    ln_kernel<<<TOK / 4, blk, 0, stream>>>(resid, attn_nw, attn_nb, ln_s);

    // 7+8 fused. inter = gelu(ln2 @ inter_w + inter_b) * (attn_out @ inter_w1)
    //            wave-split dual GEMM (R5 verified config)
    dualgemm_kernel<<<dim3(IDIM / 128, TOK / 128), blk512, 0, stream>>>(
        ln_s, inter_wt, attn_out, inter_w1t, inter_b, inter, TOK, IDIM, DIM);

    // 9. out = inter @ output_w + output_b + resid  (K=4096, N=1024)
    mgemm_kernel<float, 3, 4, 2><<<dim3(DIM / 64, TOK / 128), blk, 0, stream>>>(
        inter, output_wt, output_b, resid, out,
        nullptr, nullptr, nullptr, TOK, DIM, IDIM);
}

// Round 11
// 425.886 us; speedup vs baseline: 1.0607x; 1.0198x over previous
//
#include <hip/hip_runtime.h>
#include <hip/hip_bf16.h>

// Problem dims (fixed by reference)
#define BATCH 2
#define SEQ   2048
#define DIM   1024
#define IDIM  4096
#define NH    16
#define HD    64
#define TOK   (BATCH * SEQ)      // 4096 token rows

typedef __hip_bfloat16 bf16;

typedef short bf16x8_t __attribute__((ext_vector_type(8)));
typedef float f32x4_t  __attribute__((ext_vector_type(4)));

__device__ __forceinline__ float ldv(const float* p, size_t i) { return p[i]; }
__device__ __forceinline__ float ldv(const bf16*  p, size_t i) { return __bfloat162float(p[i]); }
__device__ __forceinline__ void  stv(float* p, size_t i, float v) { p[i] = v; }
__device__ __forceinline__ void  stv(bf16*  p, size_t i, float v) { p[i] = __float2bfloat16(v); }

__device__ __forceinline__ f32x4_t mfma16(bf16x8_t a, bf16x8_t b, f32x4_t c) {
    return __builtin_amdgcn_mfma_f32_16x16x32_bf16(a, b, c, 0, 0, 0);
}

// async global->LDS, 16B per lane; LDS dest = wave-uniform base + lane*16
__device__ __forceinline__ void gload16(const bf16* g, bf16* l) {
    __builtin_amdgcn_global_load_lds(
        (const __attribute__((address_space(1))) void*)g,
        (__attribute__((address_space(3))) void*)l, 16, 0, 0);
}

// XCD-aware block mapping (verified: cut dualgemm FETCH 277->98.6 MB).
__device__ __forceinline__ void xcd_map(int &bx, int &by) {
    const int gn  = gridDim.x;
    const int lin = blockIdx.y * gn + blockIdx.x;
    const int cx  = gn >> 3;
    const int xcd = lin & 7;
    const int slot = lin >> 3;
    bx = xcd * cx + slot % cx;
    by = slot / cx;
}

// ---------------------------------------------------------------------------
// LayerNorm row (1 wave per row): float4 loads, shfl_xor reduce, ushort4 out.
// ---------------------------------------------------------------------------
__device__ __forceinline__ void ln_one_row(const float* __restrict__ in,
                                           const float* __restrict__ w,
                                           const float* __restrict__ b,
                                           bf16* __restrict__ out,
                                           int row, int lane) {
    const float4* xr = (const float4*)(in + (size_t)row * DIM);
    float4 v[4];
    float sum = 0.f, sq = 0.f;
#pragma unroll
    for (int i = 0; i < 4; i++) {
        v[i] = xr[lane + i * 64];
        sum += v[i].x + v[i].y + v[i].z + v[i].w;
        sq  += v[i].x * v[i].x + v[i].y * v[i].y + v[i].z * v[i].z + v[i].w * v[i].w;
    }
#pragma unroll
    for (int off = 32; off >= 1; off >>= 1) {
        sum += __shfl_xor(sum, off);
        sq  += __shfl_xor(sq,  off);
    }
    const float mean = sum * (1.f / DIM);
    const float var  = fmaxf(sq * (1.f / DIM) - mean * mean, 0.f);
    const float rstd = rsqrtf(var + 1e-12f);

    const float4* wv = (const float4*)w;
    const float4* bv = (const float4*)b;
    ushort4* orow = (ushort4*)(out + (size_t)row * DIM);
#pragma unroll
    for (int i = 0; i < 4; i++) {
        const int c = lane + i * 64;
        const float4 wc = wv[c];
        const float4 bc = bv[c];
        ushort4 o;
        o.x = __bfloat16_as_ushort(__float2bfloat16((v[i].x - mean) * rstd * wc.x + bc.x));
        o.y = __bfloat16_as_ushort(__float2bfloat16((v[i].y - mean) * rstd * wc.y + bc.y));
        o.z = __bfloat16_as_ushort(__float2bfloat16((v[i].z - mean) * rstd * wc.z + bc.z));
        o.w = __bfloat16_as_ushort(__float2bfloat16((v[i].w - mean) * rstd * wc.w + bc.w));
        orow[c] = o;
    }
}

__global__ __launch_bounds__(256) void ln_kernel(const float* __restrict__ in,
                                                 const float* __restrict__ w,
                                                 const float* __restrict__ b,
                                                 bf16* __restrict__ out) {
    ln_one_row(in, w, b, out, blockIdx.x * 4 + (threadIdx.x >> 6), threadIdx.x & 63);
}

// ---------------------------------------------------------------------------
// Merged: 5 weight convert+transpose segments + ln1(x) in ONE dispatch.
// blockIdx: [0,3072) qkvw | [3072,4096) attn_ow | [4096,8192) inter_w |
// [8192,12288) inter_w1 | [12288,16384) output_w | [16384,17408) ln1 rows
// ---------------------------------------------------------------------------
__global__ __launch_bounds__(256) void wconv5ln_kernel(
        const float* __restrict__ W0, bf16* __restrict__ T0,
        const float* __restrict__ W1, bf16* __restrict__ T1,
        const float* __restrict__ W2, bf16* __restrict__ T2,
        const float* __restrict__ W3, bf16* __restrict__ T3,
        const float* __restrict__ W4, bf16* __restrict__ T4,
        const float* __restrict__ x, const float* __restrict__ nw,
        const float* __restrict__ nb, bf16* __restrict__ lnout) {
    __shared__ float tile[32][33];
    int bid = blockIdx.x;
    if (bid >= 16384) {
        ln_one_row(x, nw, nb, lnout,
                   (bid - 16384) * 4 + (threadIdx.x >> 6), threadIdx.x & 63);
        return;
    }
    const float* W; bf16* T; int K, N;
    if (bid < 3072)       { W = W0; T = T0; K = 1024; N = 3072; }
    else if (bid < 4096)  { W = W1; T = T1; K = 1024; N = 1024; bid -= 3072; }
    else if (bid < 8192)  { W = W2; T = T2; K = 1024; N = 4096; bid -= 4096; }
    else if (bid < 12288) { W = W3; T = T3; K = 1024; N = 4096; bid -= 8192; }
    else                  { W = W4; T = T4; K = 4096; N = 1024; bid -= 12288; }
    const int ntx = N >> 5;
    const int n0 = (bid % ntx) * 32;
    const int k0 = (bid / ntx) * 32;

    const int tid = threadIdx.x;
    const int c = tid & 31;
    const int r = tid >> 5;           // 0..7
#pragma unroll
    for (int i = 0; i < 4; i++)
        tile[r + i * 8][c] = W[(size_t)(k0 + r + i * 8) * N + n0 + c];
    __syncthreads();
#pragma unroll
    for (int i = 0; i < 4; i++)
        T[(size_t)(n0 + r + i * 8) * K + k0 + c] = __float2bfloat16(tile[c][r + i * 8]);
}

// ---------------------------------------------------------------------------
// MFMA GEMM (R8/R10 best-measured config, 256 thr): counted-vmcnt 2-deep
// pipeline, v1 ordering. Per iter: ds_read frags(cur) -> lgkmcnt(0)+
// sched_barrier -> s_barrier -> refill cur with tile t+2 -> MFMA (setprio)
// -> vmcnt(L) -> s_barrier. 16B-slot XOR swizzle (both-sides rule),
// XCD-aware block map. tile = (TM*32)x(TN*32), BK=32, 4 waves 2x2.
// MODE: 0 = bias(optional), 3 = bias+acc+aux,
//       4 = dual: C (bf16) = acc;  C2 (fp32) = acc + bias2 + xin
// ---------------------------------------------------------------------------
#define GBK 32

template<typename TX, int MODE, int TM, int TN>
__global__ __launch_bounds__(256) void mgemm_kernel(const bf16* __restrict__ A,
                                                    const bf16* __restrict__ Bt,
                                                    const float* __restrict__ bias,
                                                    const TX* __restrict__ aux,
                                                    TX* __restrict__ C,
                                                    const float* __restrict__ bias2,
                                                    const float* __restrict__ xin,
                                                    float* __restrict__ C2,
                                                    int M, int N, int K) {
    constexpr int TILE_M = TM * 32;
    constexpr int TILE_N = TN * 32;
    constexpr int LOADS  = TM / 2 + TN / 2;   // gload_lds per wave per stage
    __shared__ alignas(16) bf16 As[2][TILE_M][GBK];
    __shared__ alignas(16) bf16 Bs[2][TILE_N][GBK];

    const int tid  = threadIdx.x;
    const int w    = tid >> 6;
    const int lane = tid & 63;
    const int cl   = lane & 15;       // MFMA 16-group
    const int qd   = lane >> 4;       // quad
    const int wm   = w >> 1;
    const int wn   = w & 1;

    int bx, by;
    xcd_map(bx, by);

    const int row0 = by * TILE_M;
    const int col0 = bx * TILE_N;

    const int lrow = lane >> 2;
    const int lkg  = lane & 3;
    const int sslot = lkg ^ ((lrow >> 1) & 3);
    const int rds   = (cl >> 1) & 3;          // read-side swizzle for row cl

    const bf16* gA = A  + (size_t)(row0 + lrow) * K + sslot * 8;
    const bf16* gB = Bt + (size_t)(col0 + lrow) * K + sslot * 8;

    f32x4_t acc[TM][TN];
#pragma unroll
    for (int m = 0; m < TM; m++)
#pragma unroll
        for (int n = 0; n < TN; n++) acc[m][n] = {0.f, 0.f, 0.f, 0.f};

    auto stage = [&](int b, int k0) {
#pragma unroll
        for (int i = 0; i < TM / 2; i++) {
            const int r16 = (w * (TM / 2) + i) * 16;
            gload16(gA + (size_t)r16 * K + k0, &As[b][r16][0]);
        }
#pragma unroll
        for (int j = 0; j < TN / 2; j++) {
            const int r16 = (w * (TN / 2) + j) * 16;
            gload16(gB + (size_t)r16 * K + k0, &Bs[b][r16][0]);
        }
    };

    // prologue: 2 tiles in flight, wait only the first (NT >= 2 always here)
    stage(0, 0);
    stage(1, GBK);
    asm volatile("s_waitcnt vmcnt(%0)" :: "i"(LOADS) : "memory");
    __builtin_amdgcn_s_barrier();

    const int NT = K / GBK;
    for (int t = 0; t < NT; t++) {
        const int cur = t & 1;

        bf16x8_t af[TM], bfr[TN];
#pragma unroll
        for (int m = 0; m < TM; m++)
            af[m] = *(const bf16x8_t*)&As[cur][wm * (TM * 16) + m * 16 + cl][(qd ^ rds) * 8];
#pragma unroll
        for (int n = 0; n < TN; n++)
            bfr[n] = *(const bf16x8_t*)&Bs[cur][wn * (TN * 16) + n * 16 + cl][(qd ^ rds) * 8];
        asm volatile("s_waitcnt lgkmcnt(0)" ::: "memory");
        __builtin_amdgcn_sched_barrier(0);
        __builtin_amdgcn_s_barrier();     // all waves' reads of cur retired

        if (t + 2 < NT) stage(cur, (t + 2) * GBK);   // refill cur (safe now)

        __builtin_amdgcn_s_setprio(1);
#pragma unroll
        for (int m = 0; m < TM; m++)
#pragma unroll
            for (int n = 0; n < TN; n++)
                acc[m][n] = mfma16(af[m], bfr[n], acc[m][n]);
        __builtin_amdgcn_s_setprio(0);

        if (t + 1 < NT) {
            if (t + 2 < NT)
                asm volatile("s_waitcnt vmcnt(%0)" :: "i"(LOADS) : "memory");
            else
                asm volatile("s_waitcnt vmcnt(0)" ::: "memory");
            __builtin_amdgcn_s_barrier(); // buffer t+1 landed on all waves
        }
    }

    // epilogue: C/D layout col=lane&15, row=qd*4+reg
#pragma unroll
    for (int m = 0; m < TM; m++) {
#pragma unroll
        for (int n = 0; n < TN; n++) {
            const int gc = col0 + wn * (TN * 16) + n * 16 + cl;
            const float bv = (MODE != 4 && bias) ? bias[gc] : 0.f;
#pragma unroll
            for (int r = 0; r < 4; r++) {
                const int gr = row0 + wm * (TM * 16) + m * 16 + qd * 4 + r;
                float c = acc[m][n][r] + bv;
                if (MODE == 3) {
                    c += ldv(aux, (size_t)gr * N + gc);
                }
                stv(C, (size_t)gr * N + gc, c);
                if (MODE == 4) {
                    C2[(size_t)gr * N + gc] = c + bias2[gc] + xin[(size_t)gr * N + gc];
                }
            }
        }
    }
}

// ---------------------------------------------------------------------------
// Dual GEMM (fused steps 7+8), wave-split (verified R5/R9/R10: ~104 us,
// occ 33%). 512 thr = 8 waves; waves 0-3 GEMM0 (gelu path), waves 4-7 GEMM1.
// Counted-vmcnt schedule (v1 ordering); epilogue joins GEMM1 via LDS fp32
// exchange.
// ---------------------------------------------------------------------------
__global__ __launch_bounds__(512, 4) void dualgemm_kernel(const bf16* __restrict__ A0,
                                                          const bf16* __restrict__ B0t,
                                                          const bf16* __restrict__ A1,
                                                          const bf16* __restrict__ B1t,
                                                          const float* __restrict__ bias,
                                                          bf16* __restrict__ C,
                                                          int M, int N, int K) {
    // pool: staging [2 buf][4 arr][128 rows][32 bf16] = 65536 B,
    //       reused after K-loop as fp32 exchange [128][130] = 66560 B
    __shared__ alignas(16) char pool[66560];

    const int tid  = threadIdx.x;
    const int w    = tid >> 6;        // 0..7
    const int lane = tid & 63;
    const int cl   = lane & 15;
    const int qd   = lane >> 4;
    const int gsel = w >> 2;          // 0: GEMM0, 1: GEMM1
    const int g2   = w & 3;
    const int wm   = g2 >> 1;
    const int wn   = g2 & 1;

    int bx, by;
    xcd_map(bx, by);
    const int row0 = by * 128;
    const int col0 = bx * 128;

    const int lrow = lane >> 2;
    const int lkg  = lane & 3;
    const int sslot = lkg ^ ((lrow >> 1) & 3);
    const int rds   = (cl >> 1) & 3;

    // staging: wave w owns array (w>>1) in {A0,B0,A1,B1}, rowgroups (w&1)*4+j
    const int sarr = w >> 1;
    const bf16* gsrc;
    {
        const bf16* bases[4] = {A0, B0t, A1, B1t};
        const int   r0s[4]   = {row0, col0, row0, col0};
        gsrc = bases[sarr] + (size_t)(r0s[sarr] + lrow) * K + sslot * 8;
    }

    auto sptr = [&](int b, int a) -> bf16* {
        return (bf16*)(pool + b * 32768 + a * 8192);
    };

    f32x4_t acc[4][4];
#pragma unroll
    for (int m = 0; m < 4; m++)
#pragma unroll
        for (int n = 0; n < 4; n++) acc[m][n] = {0.f, 0.f, 0.f, 0.f};

    auto stage = [&](int b, int k0) {
        bf16* dst = sptr(b, sarr);
#pragma unroll
        for (int j = 0; j < 4; j++) {
            const int rg = (w & 1) * 4 + j;           // rowgroup 0..7
            gload16(gsrc + (size_t)(rg * 16) * K + k0, dst + rg * 16 * GBK);
        }
    };

    stage(0, 0);
    stage(1, GBK);
    asm volatile("s_waitcnt vmcnt(4)" ::: "memory");
    __builtin_amdgcn_s_barrier();

    const int NT = K / GBK;
    for (int t = 0; t < NT; t++) {
        const int cur = t & 1;
        const bf16* Sa = sptr(cur, gsel * 2);
        const bf16* Sb = sptr(cur, gsel * 2 + 1);

        bf16x8_t af[4], bfr[4];
#pragma unroll
        for (int m = 0; m < 4; m++)
            af[m] = *(const bf16x8_t*)&Sa[(wm * 64 + m * 16 + cl) * GBK + (qd ^ rds) * 8];
#pragma unroll
        for (int n = 0; n < 4; n++)
            bfr[n] = *(const bf16x8_t*)&Sb[(wn * 64 + n * 16 + cl) * GBK + (qd ^ rds) * 8];
        asm volatile("s_waitcnt lgkmcnt(0)" ::: "memory");
        __builtin_amdgcn_sched_barrier(0);
        __builtin_amdgcn_s_barrier();     // all waves' reads of cur retired

        if (t + 2 < NT) stage(cur, (t + 2) * GBK);

        __builtin_amdgcn_s_setprio(1);
#pragma unroll
        for (int m = 0; m < 4; m++)
#pragma unroll
            for (int n = 0; n < 4; n++)
                acc[m][n] = mfma16(af[m], bfr[n], acc[m][n]);
        __builtin_amdgcn_s_setprio(0);

        if (t + 1 < NT) {
            if (t + 2 < NT)
                asm volatile("s_waitcnt vmcnt(4)" ::: "memory");
            else
                asm volatile("s_waitcnt vmcnt(0)" ::: "memory");
            __builtin_amdgcn_s_barrier();
        }
    }

    // ---- epilogue: join GEMM1 into GEMM0 through LDS ----
    float* X = (float*)pool;          // [128][130] fp32, staging is dead
    __syncthreads();
    if (gsel == 1) {
#pragma unroll
        for (int m = 0; m < 4; m++)
#pragma unroll
            for (int n = 0; n < 4; n++)
#pragma unroll
                for (int r = 0; r < 4; r++)
                    X[(wm * 64 + m * 16 + qd * 4 + r) * 130 + wn * 64 + n * 16 + cl] =
                        acc[m][n][r];
    }
    __syncthreads();
    if (gsel == 0) {
#pragma unroll
        for (int m = 0; m < 4; m++) {
#pragma unroll
            for (int n = 0; n < 4; n++) {
                const int lc = wn * 64 + n * 16 + cl;
                const int gc = col0 + lc;
                const float bv = bias[gc];
#pragma unroll
                for (int r = 0; r < 4; r++) {
                    const int lr = wm * 64 + m * 16 + qd * 4 + r;
                    float g = acc[m][n][r] + bv;
                    g = 0.5f * g * (1.f + erff(g * 0.70710678118654752f));
                    C[(size_t)(row0 + lr) * N + gc] = __float2bfloat16(g * X[lr * 130 + lc]);
                }
            }
        }
    }
}

// ---------------------------------------------------------------------------
// V pre-transpose for attention: qkv V-slice [s][d] -> Vt[bh][d][s] (bf16).
// ---------------------------------------------------------------------------
__global__ __launch_bounds__(256) void vtrans_kernel(const bf16* __restrict__ qkv,
                                                     bf16* __restrict__ vt) {
    __shared__ bf16 t[64][72];
    const int tid = threadIdx.x;
    const int s0  = blockIdx.x * 64;
    const int bh  = blockIdx.y;
    const int bb  = bh >> 4;
    const int h   = bh & 15;
    const bf16* src = qkv + (size_t)bb * SEQ * (3 * DIM) + 2 * DIM + h * HD;
    const int r  = tid >> 3;
    const int cc = tid & 7;
#pragma unroll
    for (int i = 0; i < 2; i++)
        *(bf16x8_t*)&t[r + i * 32][cc * 8] =
            *(const bf16x8_t*)(src + (size_t)(s0 + r + i * 32) * (3 * DIM) + cc * 8);
    __syncthreads();
    bf16* dst = vt + (size_t)bh * HD * SEQ + s0;
#pragma unroll
    for (int i = 0; i < 2; i++) {
        const int d = r + i * 32;
        bf16x8_t v;
#pragma unroll
        for (int j = 0; j < 8; j++)
            ((short*)&v)[j] = *(const short*)&t[cc * 8 + j][d];
        *(bf16x8_t*)(dst + (size_t)d * SEQ + cc * 8) = v;
    }
}

// ---------------------------------------------------------------------------
// MFMA flash attention v3: wave-split occupancy (the session's proven lever,
// +34% on dualgemm). 512 thr = 8 waves, ONE 16-row q-tile per wave (the old
// per-wave qt loop becomes the wave index). Per-wave state ~halves ->
// __launch_bounds__(512,4) caps VGPR at 128 -> 2 blocks/CU = 16 waves/CU
// (was 8). LDS layout, swizzles, staging volume, barrier structure, and
// numerics byte-identical to the verified 256-thr version.
// Grid (16 qtiles of 128 rows, 32 bh).
// ---------------------------------------------------------------------------
#define KCH 64
#define NCH (SEQ / KCH)

__device__ __forceinline__ unsigned pk2(float lo, float hi) {
    unsigned a = (unsigned)__bfloat16_as_ushort(__float2bfloat16(lo));
    unsigned b = (unsigned)__bfloat16_as_ushort(__float2bfloat16(hi));
    return a | (b << 16);
}

union PAU { bf16x8_t v; unsigned u[4]; };

__global__ __launch_bounds__(512, 4) void attn_mfma_kernel(const bf16* __restrict__ qkv,
                                                           const bf16* __restrict__ vt,
                                                           const float* __restrict__ mask,
                                                           bf16* __restrict__ ctx) {
    __shared__ alignas(16) bf16 Kl[2][KCH][64];
    __shared__ alignas(16) bf16 Vl[2][KCH][64];

    const int tid  = threadIdx.x;
    const int w    = tid >> 6;        // 0..7: q-tile within block
    const int lane = tid & 63;
    const int cl   = lane & 15;
    const int qd   = lane >> 4;
    const int c7   = cl & 7;

    const int qtile = blockIdx.x;
    const int bh    = blockIdx.y;
    const int bb    = bh >> 4;
    const int h     = bh & 15;

    const bf16*  base = qkv + (size_t)bb * SEQ * (3 * DIM) + h * HD;
    const bf16*  gK   = base + DIM;
    const bf16*  gV   = vt + (size_t)bh * HD * SEQ;
    const float* mrow = mask + (size_t)bb * SEQ;

    // Q fragments (B-operand in swapped QK^T), persistent: [k-half]
    const bf16* qrow = base + (size_t)(qtile * 128 + w * 16 + cl) * (3 * DIM);
    const bf16x8_t aq0 = *(const bf16x8_t*)(qrow + qd * 8);
    const bf16x8_t aq1 = *(const bf16x8_t*)(qrow + 32 + qd * 8);

    const bf16x8_t onesv = {0x3F80, 0x3F80, 0x3F80, 0x3F80,
                            0x3F80, 0x3F80, 0x3F80, 0x3F80};

    // staging: 8 waves x 1 rowgroup each (rows w*8 + sr), 16B slots
    // pre-swizzled (scw) so LDS[row][s] = global[row][s ^ (row&7)]
    const int sr  = lane >> 3;
    const int scw = (lane & 7) ^ sr;

    {
        const int row = w * 8 + sr;
        gload16(gK + (size_t)row * (3 * DIM) + scw * 8, &Kl[0][w * 8][0]);
        gload16(gV + (size_t)row * SEQ + scw * 8, &Vl[0][w * 8][0]);
    }
    f32x4_t mkx[4];
#pragma unroll
    for (int ks = 0; ks < 4; ks++)
        mkx[ks] = *(const f32x4_t*)&mrow[ks * 16 + qd * 4];

    f32x4_t O[4] = {{0,0,0,0},{0,0,0,0},{0,0,0,0},{0,0,0,0}};
    f32x4_t li = {0.f, 0.f, 0.f, 0.f};

    for (int c = 0; c < NCH; c++) {
        __syncthreads();
        const bf16 (*Kb)[64] = Kl[c & 1];
        const bf16 (*Vb)[64] = Vl[c & 1];

        f32x4_t mk[4];
#pragma unroll
        for (int ks = 0; ks < 4; ks++) mk[ks] = mkx[ks];

        if (c + 1 < NCH) {
            bf16 (*Kn)[64] = Kl[(c + 1) & 1];
            bf16 (*Vn)[64] = Vl[(c + 1) & 1];
            const int k0n = (c + 1) * KCH;
            const int row = w * 8 + sr;
            gload16(gK + (size_t)(k0n + row) * (3 * DIM) + scw * 8, &Kn[w * 8][0]);
            gload16(gV + (size_t)row * SEQ + k0n + scw * 8, &Vn[w * 8][0]);
#pragma unroll
            for (int ks = 0; ks < 4; ks++)
                mkx[ks] = *(const f32x4_t*)&mrow[k0n + ks * 16 + qd * 4];
        }

        // K fragments (A-operand); swizzled reads
        bf16x8_t kf[4][2];
#pragma unroll
        for (int ks = 0; ks < 4; ks++) {
            kf[ks][0] = *(const bf16x8_t*)&Kb[ks * 16 + cl][(qd ^ c7) << 3];
            kf[ks][1] = *(const bf16x8_t*)&Kb[ks * 16 + cl][((4 + qd) ^ c7) << 3];
        }

        // swapped QK^T + softmax numerator, fully in-register
        unsigned Dv[4][2];
#pragma unroll
        for (int ks = 0; ks < 4; ks++) {
            f32x4_t s = {0.f, 0.f, 0.f, 0.f};
            s = mfma16(kf[ks][0], aq0, s);
            s = mfma16(kf[ks][1], aq1, s);
            const float e0 = __expf(s[0] * 0.125f + mk[ks][0]);
            const float e1 = __expf(s[1] * 0.125f + mk[ks][1]);
            const float e2 = __expf(s[2] * 0.125f + mk[ks][2]);
            const float e3 = __expf(s[3] * 0.125f + mk[ks][3]);
            Dv[ks][0] = pk2(e0, e1);
            Dv[ks][1] = pk2(e2, e3);
        }
        // C-frag -> A-frag key redistribution (permlane pair)
        PAU pa0, pa1;
#pragma unroll
        for (int rp = 0; rp < 2; rp++) {
            auto z0 = __builtin_amdgcn_permlane32_swap(Dv[0][rp], Dv[1][rp], false, false);
            auto w0 = __builtin_amdgcn_permlane16_swap(z0[0], z0[1], false, false);
            pa0.u[rp]     = w0[0];
            pa0.u[rp + 2] = w0[1];
            auto z1 = __builtin_amdgcn_permlane32_swap(Dv[2][rp], Dv[3][rp], false, false);
            auto w1 = __builtin_amdgcn_permlane16_swap(z1[0], z1[1], false, false);
            pa1.u[rp]     = w1[0];
            pa1.u[rp + 2] = w1[1];
        }
        // l row-sum via ones-MFMA
        f32x4_t ls = {0.f, 0.f, 0.f, 0.f};
        ls = mfma16(pa0.v, onesv, ls);
        ls = mfma16(pa1.v, onesv, ls);
        li += ls;

        // PV
#pragma unroll
        for (int ns = 0; ns < 4; ns++) {
            bf16x8_t v0 = *(const bf16x8_t*)&Vb[ns * 16 + cl][(qd ^ c7) << 3];
            bf16x8_t v1 = *(const bf16x8_t*)&Vb[ns * 16 + cl][((4 + qd) ^ c7) << 3];
            O[ns] = mfma16(pa0.v, v0, O[ns]);
            O[ns] = mfma16(pa1.v, v1, O[ns]);
        }
    }

#pragma unroll
    for (int r = 0; r < 4; r++) {
        const int row = qtile * 128 + w * 16 + qd * 4 + r;
        bf16* orow = ctx + (size_t)(bb * SEQ + row) * DIM + h * HD;
        const float inv = 1.f / li[r];
#pragma unroll
        for (int ns = 0; ns < 4; ns++)
            orow[ns * 16 + cl] = __float2bfloat16(O[ns][r] * inv);
    }
}

// ---------------------------------------------------------------------------
extern "C" void kernel_launch(void* const* d_in, const int* in_sizes, int n_in,
                              void* d_out, int out_size, void* d_ws, size_t ws_size,
                              hipStream_t stream) {
    const float* x        = (const float*)d_in[0];
    const float* mask     = (const float*)d_in[1];
    const float* norm_w   = (const float*)d_in[2];
    const float* norm_b   = (const float*)d_in[3];
    const float* qkvw     = (const float*)d_in[4];
    const float* qkvb     = (const float*)d_in[5];
    const float* attn_ow  = (const float*)d_in[6];
    const float* attn_ob  = (const float*)d_in[7];
    const float* attn_nw  = (const float*)d_in[8];
    const float* attn_nb  = (const float*)d_in[9];
    const float* inter_w  = (const float*)d_in[10];
    const float* inter_b  = (const float*)d_in[11];
    const float* inter_w1 = (const float*)d_in[12];
    const float* output_w = (const float*)d_in[13];
    const float* output_b = (const float*)d_in[14];

    float* out = (float*)d_out;
    bf16*  ws  = (bf16*)d_ws;

    const size_t M1 = 1024 * 1024;
    // ws layout (bf16 elems), peak 36M = 72 MB. Liveness-checked overlaps:
    //  [0,4M)    ln1 / ctx / ln2
    //  [4M,16M)  qkv (steps 2-3); [4M,20M) inter (steps 7-9)
    //  [16M,19M) qkvw_t  (steps 0-2; inside inter region, dead before step 7)
    //  [19M,20M) attn_owt (steps 0-4; same)
    //  [20M,24M) Vt (steps 3a-3b) then attn_out (steps 4-8) — Vt dead at 4
    //  [24M,28M) inter_w_t  [28M,32M) inter_w1_t  [32M,36M) output_w_t
    bf16* ln_s      = ws;
    bf16* qkv       = ws + 4 * M1;
    bf16* inter     = ws + 4 * M1;
    bf16* qkvw_t    = ws + 16 * M1;
    bf16* attn_owt  = ws + 19 * M1;
    bf16* vt        = ws + 20 * M1;
    bf16* attn_out  = ws + 20 * M1;
    bf16* inter_wt  = ws + 24 * M1;
    bf16* inter_w1t = ws + 28 * M1;
    bf16* output_wt = ws + 32 * M1;
    float* resid    = out;

    dim3 blk(256);
    dim3 blk512(512);

    // 0+1. merged weight convert+transpose (5 segments) + ln1(x), 1 launch
    wconv5ln_kernel<<<dim3(16384 + TOK / 4), blk, 0, stream>>>(
        qkvw, qkvw_t, attn_ow, attn_owt, inter_w, inter_wt,
        inter_w1, inter_w1t, output_w, output_wt,
        x, norm_w, norm_b, ln_s);

    // 2. qkv = ln1 @ qkvw + qkvb     [4096, 3072]  (24x32 = 768 blocks)
    mgemm_kernel<bf16, 0, 4, 4><<<dim3(3072 / 128, TOK / 128), blk, 0, stream>>>(
        ln_s, qkvw_t, qkvb, (const bf16*)nullptr, qkv,
        nullptr, nullptr, nullptr, TOK, 3 * DIM, DIM);

    // 3a. V pre-transpose -> Vt[bh][d][s]
    vtrans_kernel<<<dim3(SEQ / 64, BATCH * NH), blk, 0, stream>>>(qkv, vt);

    // 3b. MFMA flash attention -> ctx (reuses ln slot); 512 thr wave-split
    attn_mfma_kernel<<<dim3(SEQ / 128, BATCH * NH), blk512, 0, stream>>>(qkv, vt, mask, ln_s);

    // 4+5. attn_out = ctx @ attn_ow (no bias); resid = attn_out + attn_ob + x
    mgemm_kernel<bf16, 4, 4, 2><<<dim3(DIM / 64, TOK / 128), blk, 0, stream>>>(
        ln_s, attn_owt, (const float*)nullptr, (const bf16*)nullptr, attn_out,
        attn_ob, x, resid, TOK, DIM, DIM);

    // 6. ln2 = LN(resid)
    ln_kernel<<<TOK / 4, blk, 0, stream>>>(resid, attn_nw, attn_nb, ln_s);

    // 7+8 fused. inter = gelu(ln2 @ inter_w + inter_b) * (attn_out @ inter_w1)
    //            wave-split dual GEMM (R5 verified config)
    dualgemm_kernel<<<dim3(IDIM / 128, TOK / 128), blk512, 0, stream>>>(
        ln_s, inter_wt, attn_out, inter_w1t, inter_b, inter, TOK, IDIM, DIM);

    // 9. out = inter @ output_w + output_b + resid  (K=4096, N=1024)
    mgemm_kernel<float, 3, 4, 2><<<dim3(DIM / 64, TOK / 128), blk, 0, stream>>>(
        inter, output_wt, output_b, resid, out,
        nullptr, nullptr, nullptr, TOK, DIM, IDIM);
}